// Round 5
// baseline (21.731 us; speedup 1.0000x reference)
//
#include <hip/hip_runtime.h>

// Problem shape (fixed by reference setup_inputs)
#define BB 8
#define SS 8192
#define CC 256

#define NBLK 256                        // 1 block per CU
#define CPB (NBLK / BB)                 // 32 s-chunks per batch
#define SCHUNK (SS / CPB)               // 256 rows per block
#define NW 16                           // waves per block (1024 threads)
#define ITERS (SCHUNK / NW)             // 16 float4 row-loads per thread

// ws layout (all overwritten every call -> no init, no atomics, deterministic):
//   ws1[NBLK][CC]  per-block column partial sums   (256 KB)
//   ws2[NBLK]      per-block sum-of-squares partials (1 KB)
//   ws3[32]        per-mid-block folded scalars      (128 B)

__global__ __launch_bounds__(1024) void pcl_partial(const float* __restrict__ x,
                                                    float* __restrict__ ws1,
                                                    float* __restrict__ ws2) {
    const int blk   = blockIdx.x;
    const int b     = blk >> 5;         // blk / CPB
    const int chunk = blk & 31;
    const int s0    = chunk * SCHUNK;
    const int t = threadIdx.x;
    const int w = t >> 6;               // wave 0..15
    const int l = t & 63;               // lane

    // Wave w reads full contiguous 1 KB rows s0+w, s0+w+16, ... (16 rows).
    const float4* p = reinterpret_cast<const float4*>(
        x + ((size_t)b * SS + (size_t)(s0 + w)) * CC) + l;

    float sx0 = 0.f, sx1 = 0.f, sx2 = 0.f, sx3 = 0.f, sq = 0.f;
    #pragma unroll                       // full: 16 independent loads in flight
    for (int k = 0; k < ITERS; ++k) {
        float4 v = p[(size_t)k * (NW * CC / 4)];   // advance 16 rows
        sx0 += v.x; sx1 += v.y; sx2 += v.z; sx3 += v.w;
        sq  += v.x * v.x + v.y * v.y + v.z * v.z + v.w * v.w;
    }

    // Combine the 16 waves' column partials through LDS (16 KB).
    __shared__ float lsum[NW][CC];
    *reinterpret_cast<float4*>(&lsum[w][l * 4]) = make_float4(sx0, sx1, sx2, sx3);

    // Wave-reduce sum of squares
    for (int off = 32; off > 0; off >>= 1) sq += __shfl_down(sq, off, 64);
    __shared__ float x2buf[NW];
    if (l == 0) x2buf[w] = sq;
    __syncthreads();

    if (t < CC) {
        float col = 0.f;
        #pragma unroll
        for (int g = 0; g < NW; ++g) col += lsum[g][t];
        ws1[blk * CC + t] = col;
    }
    if (t == 0) {
        float s2 = 0.f;
        #pragma unroll
        for (int g = 0; g < NW; ++g) s2 += x2buf[g];
        ws2[blk] = s2;
    }
}

// 32 blocks: block k = (batch b = k>>2, column-group cg = k&3 covering 64 cols).
// Each block completes its 64 column sums (32 chunk-partials each), applies the
// mean^2 nonlinearity, folds 8 of the ws2 partials, writes one scalar.
__global__ __launch_bounds__(256) void pcl_mid(const float* __restrict__ ws1,
                                               const float* __restrict__ ws2,
                                               float* __restrict__ ws3) {
    const int k  = blockIdx.x;          // 0..31
    const int b  = k >> 2;
    const int c0 = (k & 3) * 64;
    const int t  = threadIdx.x;
    const int w  = t >> 6;              // 0..3 -> chunk groups of 8
    const int l  = t & 63;              // column within group

    // 8 coalesced 256B reads per wave, stride 1 KB.
    const float* base = ws1 + (size_t)(b * CPB + w * 8) * CC + c0 + l;
    float s = 0.f;
    #pragma unroll
    for (int j = 0; j < 8; ++j) s += base[(size_t)j * CC];

    __shared__ float sL[4][64];
    sL[w][l] = s;
    __syncthreads();

    if (t < 64) {
        const float col = sL[0][t] + sL[1][t] + sL[2][t] + sL[3][t];
        const float m   = col * (1.0f / SS);
        float P = -m * m * (1.0f / (BB * CC));
        if (t < 8) P += ws2[k * 8 + t] * (1.0f / ((float)BB * SS * CC));
        for (int off = 32; off > 0; off >>= 1) P += __shfl_down(P, off, 64);
        if (t == 0) ws3[k] = P;
    }
}

__global__ __launch_bounds__(64) void pcl_final(const float* __restrict__ ws3,
                                                float* __restrict__ out) {
    const int l = threadIdx.x;
    float P = (l < 32) ? ws3[l] : 0.f;
    for (int off = 32; off > 0; off >>= 1) P += __shfl_down(P, off, 64);
    if (l == 0) out[0] = 0.2f * P;   // 0.1 (weight) * 2 (pairwise->variance)
}

extern "C" void kernel_launch(void* const* d_in, const int* in_sizes, int n_in,
                              void* d_out, int out_size, void* d_ws, size_t ws_size,
                              hipStream_t stream) {
    const float* x = (const float*)d_in[0];
    float* ws1 = (float*)d_ws;              // NBLK*CC floats
    float* ws2 = ws1 + NBLK * CC;           // NBLK floats
    float* ws3 = ws2 + NBLK;                // 32 floats
    float* out = (float*)d_out;

    pcl_partial<<<NBLK, 1024, 0, stream>>>(x, ws1, ws2);
    pcl_mid<<<32, 256, 0, stream>>>(ws1, ws2, ws3);
    pcl_final<<<1, 64, 0, stream>>>(ws3, out);
}